// Round 4
// baseline (53.653 us; speedup 1.0000x reference)
//
#include <hip/hip_runtime.h>
#include <math.h>

#define BB 256
#define NN 196
#define DD 768
#define TDK 32
#define PSTRIDE 204   // tile row stride in floats: 816 B, 16B-aligned
#define NW 16         // waves per pos_conf block

typedef float f32x4 __attribute__((ext_vector_type(4)));

// Kernel 1: per-batch argmax + max-softmax over axis=1.
// 1024 threads = 16 waves. Wave w handles rows [(49w)>>2, (49(w+1))>>2).
// Lane l (l<49) owns columns 4l..4l+3 via one float4 load per row:
// 784 B per wave-instruction (full row), 4 independent online-softmax chains/lane.
__global__ __launch_bounds__(1024) void pos_conf_kernel(
    const float* __restrict__ logits,  // [B,N,N]
    float* __restrict__ conf_out,      // [B,N]
    int* __restrict__ winner_out)      // [B,N]
{
    const int b = blockIdx.x;
    const int t = threadIdx.x;
    const int w = t >> 6;
    const int l = t & 63;

    __shared__ float sm[NW][NN];
    __shared__ float ss[NW][NN];
    __shared__ int   si[NW][NN];
    __shared__ int   winner_s[NN];

    if (t < NN) winner_s[t] = -1;

    const int i0 = (49 * w) >> 2;
    const int i1 = (49 * (w + 1)) >> 2;

    if (l < 49) {
        const float* base = logits + (size_t)b * NN * NN + 4 * l;
        f32x4 m = {-INFINITY, -INFINITY, -INFINITY, -INFINITY};
        f32x4 s = {0.f, 0.f, 0.f, 0.f};
        int4 idx = make_int4(0, 0, 0, 0);
        #pragma unroll 4
        for (int i = i0; i < i1; ++i) {
            const f32x4 x = *reinterpret_cast<const f32x4*>(base + (size_t)i * NN);
            f32x4 mn;
            mn.x = fmaxf(m.x, x.x); mn.y = fmaxf(m.y, x.y);
            mn.z = fmaxf(m.z, x.z); mn.w = fmaxf(m.w, x.w);
            idx.x = (x.x > m.x) ? i : idx.x;   // strict >: first occurrence
            idx.y = (x.y > m.y) ? i : idx.y;
            idx.z = (x.z > m.z) ? i : idx.z;
            idx.w = (x.w > m.w) ? i : idx.w;
            s.x = s.x * __expf(m.x - mn.x) + __expf(x.x - mn.x);
            s.y = s.y * __expf(m.y - mn.y) + __expf(x.y - mn.y);
            s.z = s.z * __expf(m.z - mn.z) + __expf(x.z - mn.z);
            s.w = s.w * __expf(m.w - mn.w) + __expf(x.w - mn.w);
            m = mn;
        }
        const int c = 4 * l;
        sm[w][c + 0] = m.x; ss[w][c + 0] = s.x; si[w][c + 0] = idx.x;
        sm[w][c + 1] = m.y; ss[w][c + 1] = s.y; si[w][c + 1] = idx.y;
        sm[w][c + 2] = m.z; ss[w][c + 2] = s.z; si[w][c + 2] = idx.z;
        sm[w][c + 3] = m.w; ss[w][c + 3] = s.w; si[w][c + 3] = idx.w;
    }
    __syncthreads();

    if (t < NN) {
        const int j = t;
        float m = -INFINITY;
        int idx = 0;
        #pragma unroll
        for (int ww = 0; ww < NW; ++ww) {    // ascending rows: earliest chunk wins ties
            const float mg = sm[ww][j];
            if (mg > m) { m = mg; idx = si[ww][j]; }
        }
        float s = 0.0f;
        #pragma unroll
        for (int ww = 0; ww < NW; ++ww)
            s += ss[ww][j] * __expf(sm[ww][j] - m);
        conf_out[b * NN + j] = 1.0f / s;
        atomicMax(&winner_s[idx], j);        // winner[p] = max j with pos[j]==p
    }
    __syncthreads();
    if (t < NN) winner_out[b * NN + t] = winner_s[t];
}

// Kernel 2: gather rows by winner, 3-tap smooth along p, write [B, D, N].
// LDS tile stored transposed: tile[d][p], so the store phase reads contiguous p.
__global__ __launch_bounds__(256) void rearrange_kernel(
    const float* __restrict__ features,  // [B,N,D]
    const int* __restrict__ winner,      // [B,N]
    float* __restrict__ img)             // [B,D,N]
{
    const int b  = blockIdx.y;
    const int d0 = blockIdx.x * TDK;
    const int t  = threadIdx.x;

    __shared__ float tile[TDK][PSTRIDE];   // tile[d][p]

    const float* fb = features + (size_t)b * NN * DD;
    const int* wb = winner + b * NN;

    // Prefetch winner indices (breaks the dependent load->load chain).
    int w[7];
    #pragma unroll
    for (int i = 0; i < 7; ++i) {
        const int r = (t >> 3) + 32 * i;
        w[i] = (r < NN) ? wb[r] : -1;
    }

    // Load: thread (r = t>>3, d4 = (t&7)*4) loads float4 = 4 d's of gathered row r.
    const int d4 = (t & 7) * 4;
    #pragma unroll
    for (int i = 0; i < 7; ++i) {
        const int r = (t >> 3) + 32 * i;
        if (r < NN) {
            float4 v = make_float4(0.f, 0.f, 0.f, 0.f);
            if (w[i] >= 0)
                v = *reinterpret_cast<const float4*>(fb + (size_t)w[i] * DD + d0 + d4);
            tile[d4 + 0][r] = v.x;
            tile[d4 + 1][r] = v.y;
            tile[d4 + 2][r] = v.z;
            tile[d4 + 3][r] = v.w;
        }
    }
    __syncthreads();

    // Store: item q -> (d = q/49, c = q%49); writes img[b][d0+d][4c..4c+3].
    // Store address = base + q*16B: fully contiguous nontemporal float4 stores.
    #pragma unroll
    for (int it = 0; it < 7; ++it) {
        const int q = t + 256 * it;
        if (q < TDK * 49) {
            const int d = q / 49;
            const int c = q - 49 * d;
            const int p0 = 4 * c;
            const float4 ctr = *reinterpret_cast<const float4*>(&tile[d][p0]);  // 16B-aligned
            const float left  = tile[d][p0 > 0 ? p0 - 1 : 0];
            const float right = tile[d][p0 + 4 < NN ? p0 + 4 : NN - 1];
            f32x4 o;
            o.x = (p0 == 0)          ? ctr.x : (left  + ctr.x + ctr.y) * (1.0f / 3.0f);
            o.y = (ctr.x + ctr.y + ctr.z) * (1.0f / 3.0f);
            o.z = (ctr.y + ctr.z + ctr.w) * (1.0f / 3.0f);
            o.w = (p0 + 3 == NN - 1) ? ctr.w : (ctr.z + ctr.w + right) * (1.0f / 3.0f);
            float* dst = img + (size_t)b * DD * NN + (size_t)(d0 + d) * NN + p0;
            __builtin_nontemporal_store(o, reinterpret_cast<f32x4*>(dst));
        }
    }
}

extern "C" void kernel_launch(void* const* d_in, const int* in_sizes, int n_in,
                              void* d_out, int out_size, void* d_ws, size_t ws_size,
                              hipStream_t stream) {
    const float* features = (const float*)d_in[0];
    const float* logits   = (const float*)d_in[1];

    float* out  = (float*)d_out;
    float* img  = out;                              // B*D*N floats
    float* conf = out + (size_t)BB * DD * NN;       // B*N floats
    int*   winner = (int*)d_ws;                     // B*N ints

    pos_conf_kernel<<<BB, 1024, 0, stream>>>(logits, conf, winner);

    dim3 grid(DD / TDK, BB);
    rearrange_kernel<<<grid, 256, 0, stream>>>(features, winner, img);
}

// Round 5
// 50.527 us; speedup vs baseline: 1.0619x; 1.0619x over previous
//
#include <hip/hip_runtime.h>
#include <math.h>

#define BB 256
#define NN 196
#define DD 768
#define TDK 32
#define NTILES (DD / TDK)   // 24
#define PSTRIDE 204         // tile row stride in floats: 816 B, 16B-aligned
#define NW 16               // waves per block

typedef float f32x4 __attribute__((ext_vector_type(4)));

// One block per batch. Phase A: argmax + max-softmax over axis=1 (winner kept
// in LDS). Phase B: 24 d-tiles of gather -> LDS transpose -> 3-tap smooth ->
// contiguous nontemporal stores, with register prefetch of tile k+1 overlapping
// the store phase of tile k.
__global__ __launch_bounds__(1024) void fused_kernel(
    const float* __restrict__ features,  // [B,N,D]
    const float* __restrict__ logits,    // [B,N,N]
    float* __restrict__ img,             // [B,D,N]
    float* __restrict__ conf_out)        // [B,N]
{
    const int b = blockIdx.x;
    const int t = threadIdx.x;

    __shared__ float sm[NW][NN];
    __shared__ float ss[NW][NN];
    __shared__ int   si[NW][NN];
    __shared__ int   winner_s[NN];
    __shared__ float tile[TDK][PSTRIDE];   // tile[d][p]

    // ---------------- Phase A: pos + conf ----------------
    const int wv = t >> 6;
    const int l  = t & 63;

    if (t < NN) winner_s[t] = -1;

    {
        const int i0 = (49 * wv) >> 2;
        const int i1 = (49 * (wv + 1)) >> 2;
        if (l < 49) {
            const float* basep = logits + (size_t)b * NN * NN + 4 * l;
            f32x4 m = {-INFINITY, -INFINITY, -INFINITY, -INFINITY};
            f32x4 s = {0.f, 0.f, 0.f, 0.f};
            int4 idx = make_int4(0, 0, 0, 0);
            #pragma unroll 4
            for (int i = i0; i < i1; ++i) {
                const f32x4 x = *reinterpret_cast<const f32x4*>(basep + (size_t)i * NN);
                f32x4 mn;
                mn.x = fmaxf(m.x, x.x); mn.y = fmaxf(m.y, x.y);
                mn.z = fmaxf(m.z, x.z); mn.w = fmaxf(m.w, x.w);
                idx.x = (x.x > m.x) ? i : idx.x;   // strict >: first occurrence
                idx.y = (x.y > m.y) ? i : idx.y;
                idx.z = (x.z > m.z) ? i : idx.z;
                idx.w = (x.w > m.w) ? i : idx.w;
                s.x = s.x * __expf(m.x - mn.x) + __expf(x.x - mn.x);
                s.y = s.y * __expf(m.y - mn.y) + __expf(x.y - mn.y);
                s.z = s.z * __expf(m.z - mn.z) + __expf(x.z - mn.z);
                s.w = s.w * __expf(m.w - mn.w) + __expf(x.w - mn.w);
                m = mn;
            }
            const int c = 4 * l;
            sm[wv][c + 0] = m.x; ss[wv][c + 0] = s.x; si[wv][c + 0] = idx.x;
            sm[wv][c + 1] = m.y; ss[wv][c + 1] = s.y; si[wv][c + 1] = idx.y;
            sm[wv][c + 2] = m.z; ss[wv][c + 2] = s.z; si[wv][c + 2] = idx.z;
            sm[wv][c + 3] = m.w; ss[wv][c + 3] = s.w; si[wv][c + 3] = idx.w;
        }
    }
    __syncthreads();

    if (t < NN) {
        const int j = t;
        float m = -INFINITY;
        int idx = 0;
        #pragma unroll
        for (int ww = 0; ww < NW; ++ww) {    // ascending rows: earliest chunk wins ties
            const float mg = sm[ww][j];
            if (mg > m) { m = mg; idx = si[ww][j]; }
        }
        float s = 0.0f;
        #pragma unroll
        for (int ww = 0; ww < NW; ++ww)
            s += ss[ww][j] * __expf(sm[ww][j] - m);
        conf_out[b * NN + j] = 1.0f / s;
        atomicMax(&winner_s[idx], j);        // winner[p] = max j with pos[j]==p
    }
    __syncthreads();                         // winner_s ready; sm/ss/si dead

    // ---------------- Phase B: gather + smooth + transpose-store ----------------
    const float* fb = features + (size_t)b * NN * DD;
    float* ob = img + (size_t)b * DD * NN;

    // Load-side items: q in [0,1568): r = q>>3 (row), d4 = (q&7)*4 (d offset).
    const int q1_ok = (t < 1568 - 1024);
    const int r0 = t >> 3;
    const int d40 = (t & 7) * 4;
    const int r1 = (t + 1024) >> 3;
    const int d41 = ((t + 1024) & 7) * 4;

    const int w0 = winner_s[r0];
    const int w1 = q1_ok ? winner_s[r1] : -1;

    const f32x4 zero = {0.f, 0.f, 0.f, 0.f};
    f32x4 v0 = zero, v1 = zero, nv0 = zero, nv1 = zero;

    // Prefetch tile 0.
    if (w0 >= 0) v0 = *reinterpret_cast<const f32x4*>(fb + (size_t)w0 * DD + d40);
    if (w1 >= 0) v1 = *reinterpret_cast<const f32x4*>(fb + (size_t)w1 * DD + d41);

    for (int k = 0; k < NTILES; ++k) {
        // LDS transpose-write of current tile.
        tile[d40 + 0][r0] = v0.x;
        tile[d40 + 1][r0] = v0.y;
        tile[d40 + 2][r0] = v0.z;
        tile[d40 + 3][r0] = v0.w;
        if (q1_ok) {
            tile[d41 + 0][r1] = v1.x;
            tile[d41 + 1][r1] = v1.y;
            tile[d41 + 2][r1] = v1.z;
            tile[d41 + 3][r1] = v1.w;
        }

        // Issue next tile's gathers; latency hides under this tile's store phase.
        if (k + 1 < NTILES) {
            const int d0n = (k + 1) * TDK;
            nv0 = zero; nv1 = zero;
            if (w0 >= 0) nv0 = *reinterpret_cast<const f32x4*>(fb + (size_t)w0 * DD + d0n + d40);
            if (w1 >= 0) nv1 = *reinterpret_cast<const f32x4*>(fb + (size_t)w1 * DD + d0n + d41);
        }
        __syncthreads();                     // tile fully written

        // Store phase: item q -> (d = q/49, c = q%49); addr = base + 16*q bytes.
        const int d0 = k * TDK;
        #pragma unroll
        for (int it = 0; it < 2; ++it) {
            const int q = t + 1024 * it;
            if (q < TDK * 49) {
                const int d = q / 49;
                const int c = q - 49 * d;
                const int p0 = 4 * c;
                const f32x4 ctr = *reinterpret_cast<const f32x4*>(&tile[d][p0]);  // 16B-aligned
                const float left  = tile[d][p0 > 0 ? p0 - 1 : 0];
                const float right = tile[d][p0 + 4 < NN ? p0 + 4 : NN - 1];
                f32x4 o;
                o.x = (p0 == 0)          ? ctr.x : (left  + ctr.x + ctr.y) * (1.0f / 3.0f);
                o.y = (ctr.x + ctr.y + ctr.z) * (1.0f / 3.0f);
                o.z = (ctr.y + ctr.z + ctr.w) * (1.0f / 3.0f);
                o.w = (p0 + 3 == NN - 1) ? ctr.w : (ctr.z + ctr.w + right) * (1.0f / 3.0f);
                float* dst = ob + (size_t)(d0 + d) * NN + p0;
                __builtin_nontemporal_store(o, reinterpret_cast<f32x4*>(dst));
            }
        }
        v0 = nv0; v1 = nv1;
        __syncthreads();                     // store phase done before next LDS write
    }
}

extern "C" void kernel_launch(void* const* d_in, const int* in_sizes, int n_in,
                              void* d_out, int out_size, void* d_ws, size_t ws_size,
                              hipStream_t stream) {
    const float* features = (const float*)d_in[0];
    const float* logits   = (const float*)d_in[1];

    float* out  = (float*)d_out;
    float* img  = out;                              // B*D*N floats
    float* conf = out + (size_t)BB * DD * NN;       // B*N floats

    fused_kernel<<<BB, 1024, 0, stream>>>(features, logits, img, conf);
}